// Round 5
// baseline (372.737 us; speedup 1.0000x reference)
//
#include <hip/hip_runtime.h>
#include <math.h>

// Problem constants
#define BSZ 64
#define SEQ 1024
#define HID 1024
#define DOUT 1024
#define SPLIT 16           // s-chunks per batch -> 1024 score items
#define CHUNK (SEQ/SPLIT)  // 64 rows per item; 16 rows per wave

typedef float f32x4 __attribute__((ext_vector_type(4)));

// ws layout (floats):
//  scoresG  [1024][64]       @ 0
//  concatT  [2048][64]       @ 65536   (rows 0..1023 ctx^T, 1024..2047 hidden^T)
//  ctx_part [64][16][1024]   @ 196608
//  ml_part  [64][16][2]      @ 1245184
//  xpart    [8][64][1024]    @ 1247232
//  outpart  [16][64][1024]   @ 1771520
//  counters (uint)           @ 2820096  [0]=ticket, [1..64]=arr_b, [65..128]=arr_oc

// x-GEMV partials over W1 + hidden^T staging into concatT rows 1024+.
// grid (64 colgroups, 8 kchunks).
__global__ __launch_bounds__(256) void k_gemv_x(const float* __restrict__ hidden,
                                                const float* __restrict__ W1,
                                                float* __restrict__ xpart,
                                                float* __restrict__ concatT,
                                                unsigned int* __restrict__ counters) {
    __shared__ float tile[128 * 65];   // [k][b], +1 pad
    int t = threadIdx.x, lane = t & 63, wave = t >> 6;
    int k0 = blockIdx.y * 128;
    if (blockIdx.x == 0 && blockIdx.y == 0 && t < 129) counters[t] = 0;
#pragma unroll
    for (int p = 0; p < 8; ++p) {
        int b = p * 8 + (t >> 5), l5 = t & 31;
        f32x4 h = *(const f32x4*)&hidden[b * 1024 + k0 + l5 * 4];
        tile[(l5 * 4 + 0) * 65 + b] = h.x;
        tile[(l5 * 4 + 1) * 65 + b] = h.y;
        tile[(l5 * 4 + 2) * 65 + b] = h.z;
        tile[(l5 * 4 + 3) * 65 + b] = h.w;
    }
    __syncthreads();
    // cg==0 blocks also publish hidden^T into concatT rows 1024+k0 .. +128
    if (blockIdx.x == 0) {
        for (int i = t; i < 8192; i += 256)
            concatT[(size_t)(1024 + k0) * 64 + i] = tile[(i >> 6) * 65 + (i & 63)];
    }
    int c_base = blockIdx.x * 16 + (wave << 2);
    float acc[4] = {0.f, 0.f, 0.f, 0.f};
    for (int k = 0; k < 128; k += 4) {
        float v0 = tile[(k + 0) * 65 + lane];
        float v1 = tile[(k + 1) * 65 + lane];
        float v2 = tile[(k + 2) * 65 + lane];
        float v3 = tile[(k + 3) * 65 + lane];
#pragma unroll
        for (int oi = 0; oi < 4; ++oi) {
            f32x4 w = *(const f32x4*)&W1[(size_t)(c_base + oi) * 1024 + k0 + k];
            acc[oi] += w.x * v0 + w.y * v1 + w.z * v2 + w.w * v3;
        }
    }
#pragma unroll
    for (int oi = 0; oi < 4; ++oi)
        xpart[(size_t)blockIdx.y * 65536 + (size_t)lane * 1024 + c_base + oi] = acc[oi];
}

// Ticket-driven fused scores + mask + per-wave online softmax + ctx partials,
// with per-b arrival reduction (ctx combine + attn normalize) fused in.
__global__ __launch_bounds__(256, 4) void k_score(const float* __restrict__ enc,
                                                  const float* __restrict__ xpart,
                                                  const int* __restrict__ src_lens,
                                                  float* __restrict__ scoresG,
                                                  float* __restrict__ ctx_part,
                                                  float* __restrict__ ml_part,
                                                  float* __restrict__ concatT,
                                                  float* __restrict__ outAttn,
                                                  unsigned int* __restrict__ counters) {
    unsigned int* ticket = counters;
    unsigned int* arr_b  = counters + 1;
    unsigned int* arr_oc = counters + 65;
    int t = threadIdx.x, lane = t & 63, wave = t >> 6;
    __shared__ f32x4 accbuf[4 * 256];
    __shared__ float mbuf[4], lbuf[4];
    __shared__ float swgt[16];
    __shared__ unsigned int s_item, s_win;

    for (;;) {
        if (t == 0) s_item = atomicAdd(ticket, 1u);
        __syncthreads();
        unsigned int item = s_item;
        if (item == 0 && t < 64) arr_oc[t] = 0;   // init k_out's counters
        if (item >= SPLIT * BSZ) break;
        int b = item & 63, chunk = item >> 6;     // chunk-major: heavy items first

        // x[b][:] = sum of 8 K-partials (L2-hot)
        f32x4 xv[4];
#pragma unroll
        for (int i = 0; i < 4; ++i) {
            f32x4 s = (f32x4)0.f;
#pragma unroll
            for (int ks = 0; ks < 8; ++ks)
                s += ((const f32x4*)(xpart + (size_t)ks * 65536 + (size_t)b * 1024))[i * 64 + lane];
            xv[i] = s;
        }
        int len = src_lens[b];
        int s_wave0 = chunk * CHUNK + wave * 16;
        const float* encb = enc + ((size_t)b << 20);

        float m_run = -3.0e38f, l_run = 0.f;
        f32x4 acc[4];
#pragma unroll
        for (int i = 0; i < 4; ++i) acc[i] = (f32x4)0.f;

#pragma unroll 1
        for (int g = 0; g < 4; ++g) {
            int sbase = s_wave0 + g * 4;
            if (sbase >= len) {   // fully-masked group
                if (lane == 0) {
#pragma unroll
                    for (int j = 0; j < 4; ++j) scoresG[(sbase + j) * BSZ + b] = -1.0e10f;
                }
                continue;
            }
            f32x4 e[4][4];
#pragma unroll
            for (int j = 0; j < 4; ++j) {
                const f32x4* row4 = (const f32x4*)(encb + (size_t)(sbase + j) * DOUT);
#pragma unroll
                for (int i = 0; i < 4; ++i) e[j][i] = row4[i * 64 + lane];
            }
            float d0 = 0.f, d1 = 0.f, d2 = 0.f, d3 = 0.f;
#pragma unroll
            for (int i = 0; i < 4; ++i) {
                d0 += e[0][i].x * xv[i].x + e[0][i].y * xv[i].y + e[0][i].z * xv[i].z + e[0][i].w * xv[i].w;
                d1 += e[1][i].x * xv[i].x + e[1][i].y * xv[i].y + e[1][i].z * xv[i].z + e[1][i].w * xv[i].w;
                d2 += e[2][i].x * xv[i].x + e[2][i].y * xv[i].y + e[2][i].z * xv[i].z + e[2][i].w * xv[i].w;
                d3 += e[3][i].x * xv[i].x + e[3][i].y * xv[i].y + e[3][i].z * xv[i].z + e[3][i].w * xv[i].w;
            }
#pragma unroll
            for (int off = 32; off > 0; off >>= 1) {
                d0 += __shfl_xor(d0, off, 64);
                d1 += __shfl_xor(d1, off, 64);
                d2 += __shfl_xor(d2, off, 64);
                d3 += __shfl_xor(d3, off, 64);
            }
            float v0 = (sbase + 0 < len) ? d0 : 0.f; if (v0 == 0.f) v0 = -1.0e10f;
            float v1 = (sbase + 1 < len) ? d1 : 0.f; if (v1 == 0.f) v1 = -1.0e10f;
            float v2 = (sbase + 2 < len) ? d2 : 0.f; if (v2 == 0.f) v2 = -1.0e10f;
            float v3 = (sbase + 3 < len) ? d3 : 0.f; if (v3 == 0.f) v3 = -1.0e10f;
            if (lane == 0) {
                scoresG[(sbase + 0) * BSZ + b] = v0;
                scoresG[(sbase + 1) * BSZ + b] = v1;
                scoresG[(sbase + 2) * BSZ + b] = v2;
                scoresG[(sbase + 3) * BSZ + b] = v3;
            }
            float msub = fmaxf(fmaxf(v0, v1), fmaxf(v2, v3));
            float m_new = fmaxf(m_run, msub);
            float scale = __expf(m_run - m_new);
            float p0 = __expf(v0 - m_new), p1 = __expf(v1 - m_new);
            float p2 = __expf(v2 - m_new), p3 = __expf(v3 - m_new);
            l_run = l_run * scale + (p0 + p1 + p2 + p3);
            m_run = m_new;
#pragma unroll
            for (int i = 0; i < 4; ++i)
                acc[i] = acc[i] * scale + p0 * e[0][i] + p1 * e[1][i] + p2 * e[2][i] + p3 * e[3][i];
        }

        // block merge
#pragma unroll
        for (int i = 0; i < 4; ++i) accbuf[wave * 256 + i * 64 + lane] = acc[i];
        if (lane == 0) { mbuf[wave] = m_run; lbuf[wave] = l_run; }
        __syncthreads();
        float Mblk = fmaxf(fmaxf(mbuf[0], mbuf[1]), fmaxf(mbuf[2], mbuf[3]));
        float w0 = __expf(mbuf[0] - Mblk), w1 = __expf(mbuf[1] - Mblk);
        float w2 = __expf(mbuf[2] - Mblk), w3 = __expf(mbuf[3] - Mblk);
        f32x4 tot = accbuf[t] * w0 + accbuf[256 + t] * w1 + accbuf[512 + t] * w2 + accbuf[768 + t] * w3;
        ((f32x4*)(ctx_part + ((size_t)(b * SPLIT + chunk) << 10)))[t] = tot;
        if (t == 0) {
            float Lt = lbuf[0] * w0 + lbuf[1] * w1 + lbuf[2] * w2 + lbuf[3] * w3;
            ml_part[(b * SPLIT + chunk) * 2] = Mblk;
            ml_part[(b * SPLIT + chunk) * 2 + 1] = Lt;
        }

        // release + arrival
        __threadfence();
        __syncthreads();
        if (t == 0) s_win = (atomicAdd(&arr_b[b], 1u) == SPLIT - 1) ? 1u : 0u;
        __syncthreads();
        if (s_win) {
            __threadfence();  // acquire
            float M = -3.0e38f;
#pragma unroll
            for (int c = 0; c < SPLIT; ++c) M = fmaxf(M, ml_part[(b * SPLIT + c) * 2]);
            if (t < SPLIT) swgt[t] = __expf(ml_part[(b * SPLIT + t) * 2] - M);
            __syncthreads();
            float L = 0.f;
#pragma unroll
            for (int c = 0; c < SPLIT; ++c) L += swgt[c] * ml_part[(b * SPLIT + c) * 2 + 1];
            float inv = 1.f / L;
#pragma unroll
            for (int rep = 0; rep < 4; ++rep) {
                int d = rep * 256 + t;
                float a = 0.f;
#pragma unroll
                for (int c = 0; c < SPLIT; ++c)
                    a += swgt[c] * ctx_part[((size_t)(b * SPLIT + c) << 10) + d];
                concatT[d * 64 + b] = a * inv;
                outAttn[d * 64 + b] = __expf(scoresG[d * 64 + b] - M) * inv;
            }
            __syncthreads();  // protect swgt before next item reuse
        }
    }
}

// Output GEMM, full K=2048 split over 16 k-chunks, fused per-colgroup reduce+tanh.
// grid (64 colgroups, 16 kchunks).
__global__ __launch_bounds__(256) void k_out(const float* __restrict__ W2,
                                             const float* __restrict__ concatT,
                                             float* __restrict__ outpart,
                                             float* __restrict__ out,
                                             unsigned int* __restrict__ counters) {
    unsigned int* arr_oc = counters + 65;
    __shared__ float tile[128 * 64];
    __shared__ unsigned int s_win;
    int t = threadIdx.x, lane = t & 63, wave = t >> 6;
    int oc = blockIdx.x, kc = blockIdx.y;
    int k0 = kc * 128;
    {
        const f32x4* src = (const f32x4*)(concatT + (size_t)k0 * 64);
        f32x4* dst = (f32x4*)tile;
#pragma unroll
        for (int i = 0; i < 8; ++i) dst[t + i * 256] = src[t + i * 256];
    }
    __syncthreads();
    int c_base = oc * 16 + (wave << 2);
    float acc[4] = {0.f, 0.f, 0.f, 0.f};
    for (int k = 0; k < 128; k += 4) {
        float v0 = tile[(k + 0) * 64 + lane];
        float v1 = tile[(k + 1) * 64 + lane];
        float v2 = tile[(k + 2) * 64 + lane];
        float v3 = tile[(k + 3) * 64 + lane];
#pragma unroll
        for (int oi = 0; oi < 4; ++oi) {
            f32x4 w = *(const f32x4*)&W2[(size_t)(c_base + oi) * 2048 + k0 + k];
            acc[oi] += w.x * v0 + w.y * v1 + w.z * v2 + w.w * v3;
        }
    }
#pragma unroll
    for (int oi = 0; oi < 4; ++oi)
        outpart[(size_t)kc * 65536 + (size_t)lane * 1024 + c_base + oi] = acc[oi];

    __threadfence();
    __syncthreads();
    if (t == 0) s_win = (atomicAdd(&arr_oc[oc], 1u) == 15u) ? 1u : 0u;
    __syncthreads();
    if (s_win) {
        __threadfence();  // acquire
#pragma unroll
        for (int rep = 0; rep < 4; ++rep) {
            int idx = rep * 256 + t;            // idx = b*16 + o_local
            int b = idx >> 4, o = oc * 16 + (idx & 15);
            float s = 0.f;
#pragma unroll
            for (int k2 = 0; k2 < 16; ++k2)
                s += outpart[(size_t)k2 * 65536 + (size_t)b * 1024 + o];
            out[b * 1024 + o] = tanhf(s);
        }
    }
}

extern "C" void kernel_launch(void* const* d_in, const int* in_sizes, int n_in,
                              void* d_out, int out_size, void* d_ws, size_t ws_size,
                              hipStream_t stream) {
    const float* hidden   = (const float*)d_in[0];
    const float* enc      = (const float*)d_in[1];
    const int*   src_lens = (const int*)d_in[2];
    const float* W1       = (const float*)d_in[3];
    const float* W2       = (const float*)d_in[4];
    float* out     = (float*)d_out;        // [64][1024]
    float* outAttn = out + 65536;          // [1024][64]

    float* ws       = (float*)d_ws;
    float* scoresG  = ws;                  // [1024][64]
    float* concatT  = ws + 65536;          // [2048][64]
    float* ctx_part = ws + 196608;         // [64][16][1024]
    float* ml_part  = ws + 1245184;        // [64][16][2]
    float* xpart    = ws + 1247232;        // [8][64][1024]
    float* outpart  = ws + 1771520;        // [16][64][1024]
    unsigned int* counters = (unsigned int*)(ws + 2820096);

    k_gemv_x<<<dim3(64, 8), 256, 0, stream>>>(hidden, W1, xpart, concatT, counters);
    k_score<<<dim3(SPLIT * BSZ), 256, 0, stream>>>(enc, xpart, src_lens, scoresG,
                                                   ctx_part, ml_part, concatT, outAttn, counters);
    k_out<<<dim3(64, 16), 256, 0, stream>>>(W2, concatT, outpart, out, counters);
}

// Round 6
// 101.695 us; speedup vs baseline: 3.6653x; 3.6653x over previous
//
#include <hip/hip_runtime.h>
#include <math.h>

// Problem constants
#define BSZ 64
#define SEQ 1024
#define HID 1024
#define DOUT 1024
#define SPLIT 16           // s-chunks per batch -> grid (16,64) for k_score
#define CHUNK (SEQ/SPLIT)  // 64 rows per block; 16 rows per wave

typedef float f32x4 __attribute__((ext_vector_type(4)));

// ws layout (floats):
//  scoresG  [1024][64]       @ 0
//  concatT  [2048][64]       @ 65536   (rows 0..1023 ctx^T, 1024..2047 hidden^T)
//  ctx_part [64][16][1024]   @ 196608
//  ml_part  [64][16][2]      @ 1245184
//  xpart    [8][64][1024]    @ 1247232
// total 1771520 floats ~= 6.8 MiB

// x-GEMV partials over W1. grid (64 colgroups, 8 kchunks).
__global__ __launch_bounds__(256) void k_gemv_x(const float* __restrict__ hidden,
                                                const float* __restrict__ W1,
                                                float* __restrict__ xpart) {
    __shared__ float tile[128 * 65];   // [k][b], +1 pad
    int t = threadIdx.x, lane = t & 63, wave = t >> 6;
    int k0 = blockIdx.y * 128;
#pragma unroll
    for (int p = 0; p < 8; ++p) {
        int b = p * 8 + (t >> 5), l5 = t & 31;
        f32x4 h = *(const f32x4*)&hidden[b * 1024 + k0 + l5 * 4];
        tile[(l5 * 4 + 0) * 65 + b] = h.x;
        tile[(l5 * 4 + 1) * 65 + b] = h.y;
        tile[(l5 * 4 + 2) * 65 + b] = h.z;
        tile[(l5 * 4 + 3) * 65 + b] = h.w;
    }
    __syncthreads();
    int c_base = blockIdx.x * 16 + (wave << 2);
    float acc[4] = {0.f, 0.f, 0.f, 0.f};
    for (int k = 0; k < 128; k += 4) {
        float v0 = tile[(k + 0) * 65 + lane];
        float v1 = tile[(k + 1) * 65 + lane];
        float v2 = tile[(k + 2) * 65 + lane];
        float v3 = tile[(k + 3) * 65 + lane];
#pragma unroll
        for (int oi = 0; oi < 4; ++oi) {
            f32x4 w = *(const f32x4*)&W1[(size_t)(c_base + oi) * 1024 + k0 + k];
            acc[oi] += w.x * v0 + w.y * v1 + w.z * v2 + w.w * v3;
        }
    }
#pragma unroll
    for (int oi = 0; oi < 4; ++oi)
        xpart[(size_t)blockIdx.y * 65536 + (size_t)lane * 1024 + c_base + oi] = acc[oi];
}

// Barrier-free fused scores + mask + per-wave online softmax + ctx partials.
// Branch-free group loop: trip count from len (monotone masked tail skipped).
__global__ __launch_bounds__(256, 4) void k_score(const float* __restrict__ enc,
                                                  const float* __restrict__ xpart,
                                                  const int* __restrict__ src_lens,
                                                  float* __restrict__ scoresG,
                                                  float* __restrict__ ctx_part,
                                                  float* __restrict__ ml_part) {
    int b = blockIdx.y, chunk = blockIdx.x;
    int t = threadIdx.x, lane = t & 63, wave = t >> 6;
    __shared__ f32x4 accbuf[4 * 256];
    __shared__ float mbuf[4], lbuf[4];

    // x[b][:] = sum of 8 K-partials (L2-hot)
    f32x4 xv[4];
#pragma unroll
    for (int i = 0; i < 4; ++i) {
        f32x4 s = (f32x4)0.f;
#pragma unroll
        for (int ks = 0; ks < 8; ++ks)
            s += ((const f32x4*)(xpart + (size_t)ks * 65536 + (size_t)b * 1024))[i * 64 + lane];
        xv[i] = s;
    }
    int len = src_lens[b];
    int s_wave0 = chunk * CHUNK + wave * 16;
    const float* encb = enc + ((size_t)b << 20);

    int rem = len - s_wave0;
    int ng = (rem + 3) >> 2;               // arithmetic shift: negative -> <=0
    ng = ng < 0 ? 0 : (ng > 4 ? 4 : ng);

    float m_run = -3.0e38f, l_run = 0.f;
    f32x4 acc[4];
#pragma unroll
    for (int i = 0; i < 4; ++i) acc[i] = (f32x4)0.f;

    for (int g = 0; g < ng; ++g) {
        int sbase = s_wave0 + g * 4;
        f32x4 e[4][4];
#pragma unroll
        for (int j = 0; j < 4; ++j) {
            const f32x4* row4 = (const f32x4*)(encb + (size_t)(sbase + j) * DOUT);
#pragma unroll
            for (int i = 0; i < 4; ++i) e[j][i] = row4[i * 64 + lane];
        }
        float d0 = 0.f, d1 = 0.f, d2 = 0.f, d3 = 0.f;
#pragma unroll
        for (int i = 0; i < 4; ++i) {
            d0 += e[0][i].x * xv[i].x + e[0][i].y * xv[i].y + e[0][i].z * xv[i].z + e[0][i].w * xv[i].w;
            d1 += e[1][i].x * xv[i].x + e[1][i].y * xv[i].y + e[1][i].z * xv[i].z + e[1][i].w * xv[i].w;
            d2 += e[2][i].x * xv[i].x + e[2][i].y * xv[i].y + e[2][i].z * xv[i].z + e[2][i].w * xv[i].w;
            d3 += e[3][i].x * xv[i].x + e[3][i].y * xv[i].y + e[3][i].z * xv[i].z + e[3][i].w * xv[i].w;
        }
#pragma unroll
        for (int off = 32; off > 0; off >>= 1) {
            d0 += __shfl_xor(d0, off, 64);
            d1 += __shfl_xor(d1, off, 64);
            d2 += __shfl_xor(d2, off, 64);
            d3 += __shfl_xor(d3, off, 64);
        }
        // mask: invalid rows -> 0; any exact zero -> -1e10 (reference quirk)
        float v0 = (sbase + 0 < len) ? d0 : 0.f; if (v0 == 0.f) v0 = -1.0e10f;
        float v1 = (sbase + 1 < len) ? d1 : 0.f; if (v1 == 0.f) v1 = -1.0e10f;
        float v2 = (sbase + 2 < len) ? d2 : 0.f; if (v2 == 0.f) v2 = -1.0e10f;
        float v3 = (sbase + 3 < len) ? d3 : 0.f; if (v3 == 0.f) v3 = -1.0e10f;
        if (lane == 0) {
            scoresG[(sbase + 0) * BSZ + b] = v0;
            scoresG[(sbase + 1) * BSZ + b] = v1;
            scoresG[(sbase + 2) * BSZ + b] = v2;
            scoresG[(sbase + 3) * BSZ + b] = v3;
        }
        float msub = fmaxf(fmaxf(v0, v1), fmaxf(v2, v3));
        float m_new = fmaxf(m_run, msub);
        float scale = __expf(m_run - m_new);
        float p0 = __expf(v0 - m_new), p1 = __expf(v1 - m_new);
        float p2 = __expf(v2 - m_new), p3 = __expf(v3 - m_new);
        l_run = l_run * scale + (p0 + p1 + p2 + p3);
        m_run = m_new;
#pragma unroll
        for (int i = 0; i < 4; ++i)
            acc[i] = acc[i] * scale + p0 * e[0][i] + p1 * e[1][i] + p2 * e[2][i] + p3 * e[3][i];
    }

    // block merge (single barrier)
#pragma unroll
    for (int i = 0; i < 4; ++i) accbuf[wave * 256 + i * 64 + lane] = acc[i];
    if (lane == 0) { mbuf[wave] = m_run; lbuf[wave] = l_run; }
    __syncthreads();
    float M = fmaxf(fmaxf(mbuf[0], mbuf[1]), fmaxf(mbuf[2], mbuf[3]));
    float w0 = __expf(mbuf[0] - M), w1 = __expf(mbuf[1] - M);
    float w2 = __expf(mbuf[2] - M), w3 = __expf(mbuf[3] - M);
    f32x4 tot = accbuf[t] * w0 + accbuf[256 + t] * w1 + accbuf[512 + t] * w2 + accbuf[768 + t] * w3;
    ((f32x4*)(ctx_part + ((size_t)(b * SPLIT + chunk) << 10)))[t] = tot;
    if (t == 0) {
        float Lt = lbuf[0] * w0 + lbuf[1] * w1 + lbuf[2] * w2 + lbuf[3] * w3;
        ml_part[(b * SPLIT + chunk) * 2] = M;
        ml_part[(b * SPLIT + chunk) * 2 + 1] = Lt;
    }
}

// Per-batch combine + attn normalize + hidden^T staging into concatT rows 1024+.
// grid 256: b = bid>>2, quarter = bid&3.
__global__ __launch_bounds__(256) void k_reduce_attn(const float* __restrict__ ctx_part,
                                                     const float* __restrict__ ml_part,
                                                     const float* __restrict__ scoresG,
                                                     const int* __restrict__ src_lens,
                                                     const float* __restrict__ hidden,
                                                     float* __restrict__ concatT,
                                                     float* __restrict__ outAttn) {
    int b = blockIdx.x >> 2, q = blockIdx.x & 3, t = threadIdx.x;
    int len = src_lens[b];
    float M = -3.0e38f;
#pragma unroll
    for (int c = 0; c < SPLIT; ++c) M = fmaxf(M, ml_part[(b * SPLIT + c) * 2]);
    float L = 0.f;
    float wgt[SPLIT];
#pragma unroll
    for (int c = 0; c < SPLIT; ++c) {
        float e = __expf(ml_part[(b * SPLIT + c) * 2] - M);
        wgt[c] = e;
        L += ml_part[(b * SPLIT + c) * 2 + 1] * e;
    }
    float inv = 1.f / L;
    int d = q * 256 + t;
    float acc = 0.f;
#pragma unroll
    for (int c = 0; c < SPLIT; ++c)
        acc += wgt[c] * ctx_part[((size_t)(b * SPLIT + c) << 10) + d];
    concatT[d * BSZ + b] = acc * inv;
    // masked rows: reference exp(-1e10 - M) underflows to exactly 0
    outAttn[d * BSZ + b] = (d < len) ? __expf(scoresG[d * BSZ + b] - M) * inv : 0.f;
    // hidden^T staging (d doubles as k)
    concatT[(1024 + d) * BSZ + b] = hidden[b * 1024 + d];
}

// Output GEMM, full K=2048 in one kernel. grid 256, 1 col/wave, lane = b.
// W2 row reads are wave-uniform -> scalar loads; concatT chunk staged in LDS.
__global__ __launch_bounds__(256) void k_out(const float* __restrict__ W2,
                                             const float* __restrict__ concatT,
                                             float* __restrict__ out) {
    __shared__ float tile[128 * 64];   // 32 KiB
    int t = threadIdx.x, lane = t & 63, wave = t >> 6;
    int c = blockIdx.x * 4 + wave;
    const float* wrow = W2 + (size_t)c * 2048;
    float acc = 0.f;
    for (int kc = 0; kc < 16; ++kc) {
        int k0 = kc * 128;
        __syncthreads();
        const f32x4* src = (const f32x4*)(concatT + (size_t)k0 * 64);
        f32x4* dst = (f32x4*)tile;
#pragma unroll
        for (int i = 0; i < 8; ++i) dst[t + i * 256] = src[t + i * 256];
        __syncthreads();
#pragma unroll 4
        for (int k = 0; k < 128; k += 4) {
            f32x4 w = *(const f32x4*)&wrow[k0 + k];
            acc += w.x * tile[(k + 0) * 64 + lane] + w.y * tile[(k + 1) * 64 + lane]
                 + w.z * tile[(k + 2) * 64 + lane] + w.w * tile[(k + 3) * 64 + lane];
        }
    }
    out[lane * 1024 + c] = tanhf(acc);
}

extern "C" void kernel_launch(void* const* d_in, const int* in_sizes, int n_in,
                              void* d_out, int out_size, void* d_ws, size_t ws_size,
                              hipStream_t stream) {
    const float* hidden   = (const float*)d_in[0];
    const float* enc      = (const float*)d_in[1];
    const int*   src_lens = (const int*)d_in[2];
    const float* W1       = (const float*)d_in[3];
    const float* W2       = (const float*)d_in[4];
    float* out     = (float*)d_out;        // [64][1024]
    float* outAttn = out + 65536;          // [1024][64]

    float* ws       = (float*)d_ws;
    float* scoresG  = ws;                  // [1024][64]
    float* concatT  = ws + 65536;          // [2048][64]
    float* ctx_part = ws + 196608;         // [64][16][1024]
    float* ml_part  = ws + 1245184;        // [64][16][2]
    float* xpart    = ws + 1247232;        // [8][64][1024]

    k_gemv_x<<<dim3(64, 8), 256, 0, stream>>>(hidden, W1, xpart);
    k_score<<<dim3(SPLIT, BSZ), 256, 0, stream>>>(enc, xpart, src_lens, scoresG, ctx_part, ml_part);
    k_reduce_attn<<<256, 256, 0, stream>>>(ctx_part, ml_part, scoresG, src_lens, hidden, concatT, outAttn);
    k_out<<<256, 256, 0, stream>>>(W2, concatT, out);
}

// Round 7
// 101.169 us; speedup vs baseline: 3.6843x; 1.0052x over previous
//
#include <hip/hip_runtime.h>
#include <math.h>

// Problem constants
#define BSZ 64
#define SEQ 1024
#define HID 1024
#define DOUT 1024
#define SPLIT 16           // s-chunks per batch -> grid (16,64) for k_score
#define CHUNK (SEQ/SPLIT)  // 64 rows per block; 16 rows per wave

typedef float f32x4 __attribute__((ext_vector_type(4)));

// ws layout (floats):
//  scoresG  [64][1024]       @ 0         (raw masked scores, [b][s])
//  ctx_part [64][16][1024]   @ 65536
//  ml_part  [64][16][2]      @ 1114112
//  xpart    [8][64][1024]    @ 1116160
//  outpart8 [8][64][1024]    @ 1640448   (hidden-half of out GEMM, k-split partials)
// total 2164736 floats ~= 8.3 MiB

// GEMV over hidden: x-partials (W1) AND out-partials for the hidden half of
// W2 (cols k>=1024), sharing one staged hidden tile.
// grid (128, 8): bx<64 -> x cols, bx>=64 -> out cols. by = 128-wide k-chunk.
__global__ __launch_bounds__(256) void k_gemv_hid(const float* __restrict__ hidden,
                                                  const float* __restrict__ W1,
                                                  const float* __restrict__ W2,
                                                  float* __restrict__ xpart,
                                                  float* __restrict__ outpart8) {
    __shared__ float tile[128 * 65];   // [k][b], +1 pad
    int t = threadIdx.x, lane = t & 63, wave = t >> 6;
    int k0 = blockIdx.y * 128;
#pragma unroll
    for (int p = 0; p < 8; ++p) {
        int b = p * 8 + (t >> 5), l5 = t & 31;
        f32x4 h = *(const f32x4*)&hidden[b * 1024 + k0 + l5 * 4];
        tile[(l5 * 4 + 0) * 65 + b] = h.x;
        tile[(l5 * 4 + 1) * 65 + b] = h.y;
        tile[(l5 * 4 + 2) * 65 + b] = h.z;
        tile[(l5 * 4 + 3) * 65 + b] = h.w;
    }
    __syncthreads();
    bool isX = blockIdx.x < 64;
    int cg = isX ? blockIdx.x : blockIdx.x - 64;
    int c_base = cg * 16 + (wave << 2);
    const float* w0p = isX ? (W1 + (size_t)c_base * 1024 + k0)
                           : (W2 + (size_t)c_base * 2048 + 1024 + k0);
    size_t ldw = isX ? 1024 : 2048;
    float acc[4] = {0.f, 0.f, 0.f, 0.f};
    for (int k = 0; k < 128; k += 4) {
        float v0 = tile[(k + 0) * 65 + lane];
        float v1 = tile[(k + 1) * 65 + lane];
        float v2 = tile[(k + 2) * 65 + lane];
        float v3 = tile[(k + 3) * 65 + lane];
#pragma unroll
        for (int oi = 0; oi < 4; ++oi) {
            f32x4 w = *(const f32x4*)&w0p[oi * ldw + k];
            acc[oi] += w.x * v0 + w.y * v1 + w.z * v2 + w.w * v3;
        }
    }
    float* dst = isX ? (xpart + (size_t)blockIdx.y * 65536)
                     : (outpart8 + (size_t)blockIdx.y * 65536);
#pragma unroll
    for (int oi = 0; oi < 4; ++oi)
        dst[(size_t)lane * 1024 + c_base + oi] = acc[oi];
}

// Barrier-free fused scores + mask + per-wave online softmax + ctx partials.
// Trip count derived from len (fully-masked tail groups skipped entirely).
__global__ __launch_bounds__(256, 4) void k_score(const float* __restrict__ enc,
                                                  const float* __restrict__ xpart,
                                                  const int* __restrict__ src_lens,
                                                  float* __restrict__ scoresG,
                                                  float* __restrict__ ctx_part,
                                                  float* __restrict__ ml_part) {
    int b = blockIdx.y, chunk = blockIdx.x;
    int t = threadIdx.x, lane = t & 63, wave = t >> 6;
    __shared__ f32x4 accbuf[4 * 256];
    __shared__ float mbuf[4], lbuf[4];

    // x[b][:] = sum of 8 K-partials (L2/L3-hot)
    f32x4 xv[4];
#pragma unroll
    for (int i = 0; i < 4; ++i) {
        f32x4 s = (f32x4)0.f;
#pragma unroll
        for (int ks = 0; ks < 8; ++ks)
            s += ((const f32x4*)(xpart + (size_t)ks * 65536 + (size_t)b * 1024))[i * 64 + lane];
        xv[i] = s;
    }
    int len = src_lens[b];
    int s_wave0 = chunk * CHUNK + wave * 16;
    const float* encb = enc + ((size_t)b << 20);

    int rem = len - s_wave0;
    int ng = (rem + 3) >> 2;
    ng = ng < 0 ? 0 : (ng > 4 ? 4 : ng);

    float m_run = -3.0e38f, l_run = 0.f;
    f32x4 acc[4];
#pragma unroll
    for (int i = 0; i < 4; ++i) acc[i] = (f32x4)0.f;

    for (int g = 0; g < ng; ++g) {
        int sbase = s_wave0 + g * 4;
        f32x4 e[4][4];
#pragma unroll
        for (int j = 0; j < 4; ++j) {
            const f32x4* row4 = (const f32x4*)(encb + (size_t)(sbase + j) * DOUT);
#pragma unroll
            for (int i = 0; i < 4; ++i) e[j][i] = row4[i * 64 + lane];
        }
        float d0 = 0.f, d1 = 0.f, d2 = 0.f, d3 = 0.f;
#pragma unroll
        for (int i = 0; i < 4; ++i) {
            d0 += e[0][i].x * xv[i].x + e[0][i].y * xv[i].y + e[0][i].z * xv[i].z + e[0][i].w * xv[i].w;
            d1 += e[1][i].x * xv[i].x + e[1][i].y * xv[i].y + e[1][i].z * xv[i].z + e[1][i].w * xv[i].w;
            d2 += e[2][i].x * xv[i].x + e[2][i].y * xv[i].y + e[2][i].z * xv[i].z + e[2][i].w * xv[i].w;
            d3 += e[3][i].x * xv[i].x + e[3][i].y * xv[i].y + e[3][i].z * xv[i].z + e[3][i].w * xv[i].w;
        }
#pragma unroll
        for (int off = 32; off > 0; off >>= 1) {
            d0 += __shfl_xor(d0, off, 64);
            d1 += __shfl_xor(d1, off, 64);
            d2 += __shfl_xor(d2, off, 64);
            d3 += __shfl_xor(d3, off, 64);
        }
        // mask: invalid rows -> 0; any exact zero -> -1e10 (reference quirk)
        float v0 = (sbase + 0 < len) ? d0 : 0.f; if (v0 == 0.f) v0 = -1.0e10f;
        float v1 = (sbase + 1 < len) ? d1 : 0.f; if (v1 == 0.f) v1 = -1.0e10f;
        float v2 = (sbase + 2 < len) ? d2 : 0.f; if (v2 == 0.f) v2 = -1.0e10f;
        float v3 = (sbase + 3 < len) ? d3 : 0.f; if (v3 == 0.f) v3 = -1.0e10f;
        if (lane == 0) {
            f32x4 sv = {v0, v1, v2, v3};
            *(f32x4*)&scoresG[b * 1024 + sbase] = sv;
        }
        float msub = fmaxf(fmaxf(v0, v1), fmaxf(v2, v3));
        float m_new = fmaxf(m_run, msub);
        float scale = __expf(m_run - m_new);
        float p0 = __expf(v0 - m_new), p1 = __expf(v1 - m_new);
        float p2 = __expf(v2 - m_new), p3 = __expf(v3 - m_new);
        l_run = l_run * scale + (p0 + p1 + p2 + p3);
        m_run = m_new;
#pragma unroll
        for (int i = 0; i < 4; ++i)
            acc[i] = acc[i] * scale + p0 * e[0][i] + p1 * e[1][i] + p2 * e[2][i] + p3 * e[3][i];
    }

    // block merge (single barrier)
#pragma unroll
    for (int i = 0; i < 4; ++i) accbuf[wave * 256 + i * 64 + lane] = acc[i];
    if (lane == 0) { mbuf[wave] = m_run; lbuf[wave] = l_run; }
    __syncthreads();
    float M = fmaxf(fmaxf(mbuf[0], mbuf[1]), fmaxf(mbuf[2], mbuf[3]));
    float w0 = __expf(mbuf[0] - M), w1 = __expf(mbuf[1] - M);
    float w2 = __expf(mbuf[2] - M), w3 = __expf(mbuf[3] - M);
    f32x4 tot = accbuf[t] * w0 + accbuf[256 + t] * w1 + accbuf[512 + t] * w2 + accbuf[768 + t] * w3;
    ((f32x4*)(ctx_part + ((size_t)(b * SPLIT + chunk) << 10)))[t] = tot;
    if (t == 0) {
        float Lt = lbuf[0] * w0 + lbuf[1] * w1 + lbuf[2] * w2 + lbuf[3] * w3;
        ml_part[(b * SPLIT + chunk) * 2] = M;
        ml_part[(b * SPLIT + chunk) * 2 + 1] = Lt;
    }
}

// Fused finale: ctx-combine + attn-normalize + ctx-half GEMV + hidden-half
// partial sum + tanh. grid 256 = 32 b-pairs x 8 o-chunks(128). block 256.
// Two batches share every W2 row read (halves L2 re-reads).
__global__ __launch_bounds__(256) void k_outfinal(const float* __restrict__ ctx_part,
                                                  const float* __restrict__ ml_part,
                                                  const float* __restrict__ scoresG,
                                                  const int* __restrict__ src_lens,
                                                  const float* __restrict__ outpart8,
                                                  const float* __restrict__ W2,
                                                  float* __restrict__ out,
                                                  float* __restrict__ outAttn) {
    int bp = blockIdx.x >> 3, oq = blockIdx.x & 7;
    int b0 = bp * 2, b1 = b0 + 1;
    int t = threadIdx.x, lane = t & 63, wave = t >> 6;
    __shared__ float ctx_s[2][1024];
    __shared__ float osum[2][128];

    // softmax stats + ctx combine for both batches
    float inv[2];
#pragma unroll
    for (int bs = 0; bs < 2; ++bs) {
        int b = b0 + bs;
        float M = -3.0e38f;
#pragma unroll
        for (int c = 0; c < SPLIT; ++c) M = fmaxf(M, ml_part[(b * SPLIT + c) * 2]);
        float L = 0.f;
        float wgt[SPLIT];
#pragma unroll
        for (int c = 0; c < SPLIT; ++c) {
            float e = __expf(ml_part[(b * SPLIT + c) * 2] - M);
            wgt[c] = e;
            L += ml_part[(b * SPLIT + c) * 2 + 1] * e;
        }
        inv[bs] = 1.f / L;
#pragma unroll
        for (int r = 0; r < 4; ++r) {
            int d = r * 256 + t;
            float a = 0.f;
#pragma unroll
            for (int c = 0; c < SPLIT; ++c)
                a += wgt[c] * ctx_part[((size_t)(b * SPLIT + c) << 10) + d];
            ctx_s[bs][d] = a * inv[bs];
        }
        if (oq == 0) {   // attn normalize: masked rows underflow to exactly 0
            int len = src_lens[b];
#pragma unroll
            for (int r = 0; r < 4; ++r) {
                int s = r * 256 + t;
                outAttn[s * BSZ + b] = (s < len) ? __expf(scoresG[b * 1024 + s] - M) * inv[bs] : 0.f;
            }
        }
    }

    // hidden-half seed: thread t -> (bsel = t>>7, o_local = t&127)
    int oblk = oq * 128;
    int bsel = t >> 7, o_loc = t & 127;
    float hseed = 0.f;
#pragma unroll
    for (int ks = 0; ks < 8; ++ks)
        hseed += outpart8[(size_t)ks * 65536 + (size_t)(b0 + bsel) * 1024 + oblk + o_loc];
    __syncthreads();

    // ctx-half GEMV: wave w handles o in [oblk + w*32, +32), both batches per W row.
#pragma unroll 2
    for (int i = 0; i < 32; ++i) {
        int o = oblk + wave * 32 + i;
        const f32x4* w4 = (const f32x4*)(W2 + (size_t)o * 2048);
        float s0 = 0.f, s1 = 0.f;
#pragma unroll
        for (int j = 0; j < 4; ++j) {
            f32x4 w = w4[j * 64 + lane];
            f32x4 c0 = ((const f32x4*)ctx_s[0])[j * 64 + lane];
            f32x4 c1 = ((const f32x4*)ctx_s[1])[j * 64 + lane];
            s0 += w.x * c0.x + w.y * c0.y + w.z * c0.z + w.w * c0.w;
            s1 += w.x * c1.x + w.y * c1.y + w.z * c1.z + w.w * c1.w;
        }
#pragma unroll
        for (int off = 32; off > 0; off >>= 1) {
            s0 += __shfl_xor(s0, off, 64);
            s1 += __shfl_xor(s1, off, 64);
        }
        if (lane == 0) { osum[0][wave * 32 + i] = s0; osum[1][wave * 32 + i] = s1; }
    }
    __syncthreads();
    out[(size_t)(b0 + bsel) * 1024 + oblk + o_loc] = tanhf(osum[bsel][o_loc] + hseed);
}

extern "C" void kernel_launch(void* const* d_in, const int* in_sizes, int n_in,
                              void* d_out, int out_size, void* d_ws, size_t ws_size,
                              hipStream_t stream) {
    const float* hidden   = (const float*)d_in[0];
    const float* enc      = (const float*)d_in[1];
    const int*   src_lens = (const int*)d_in[2];
    const float* W1       = (const float*)d_in[3];
    const float* W2       = (const float*)d_in[4];
    float* out     = (float*)d_out;        // [64][1024]
    float* outAttn = out + 65536;          // [1024][64]

    float* ws       = (float*)d_ws;
    float* scoresG  = ws;                  // [64][1024]
    float* ctx_part = ws + 65536;          // [64][16][1024]
    float* ml_part  = ws + 1114112;        // [64][16][2]
    float* xpart    = ws + 1116160;        // [8][64][1024]
    float* outpart8 = ws + 1640448;        // [8][64][1024]

    k_gemv_hid<<<dim3(128, 8), 256, 0, stream>>>(hidden, W1, W2, xpart, outpart8);
    k_score<<<dim3(SPLIT, BSZ), 256, 0, stream>>>(enc, xpart, src_lens, scoresG, ctx_part, ml_part);
    k_outfinal<<<256, 256, 0, stream>>>(ctx_part, ml_part, scoresG, src_lens, outpart8, W2, out, outAttn);
}

// Round 8
// 97.989 us; speedup vs baseline: 3.8039x; 1.0325x over previous
//
#include <hip/hip_runtime.h>
#include <math.h>

// Problem constants
#define BSZ 64
#define SEQ 1024
#define HID 1024
#define DOUT 1024
#define SPLIT 16           // s-chunks per batch -> grid (16,64) for k_score
#define CHUNK (SEQ/SPLIT)  // 64 rows per block; 16 rows per wave

typedef float f32x4 __attribute__((ext_vector_type(4)));

// ws layout (floats):
//  scoresG  [64][1024]       @ 0         (raw masked scores, [b][s])
//  ctx_part [64][16][1024]   @ 65536
//  ml_part  [64][16][2]      @ 1114112
//  xpart    [8][64][1024]    @ 1116160
//  outpart8 [8][64][1024]    @ 1640448   (hidden-half of out GEMM, k-split partials)

// GEMV over hidden: x-partials (W1) AND out-partials for the hidden half of
// W2 (cols k>=1024), sharing one staged hidden tile.
// grid (128, 8): bx<64 -> x cols, bx>=64 -> out cols. by = 128-wide k-chunk.
__global__ __launch_bounds__(256) void k_gemv_hid(const float* __restrict__ hidden,
                                                  const float* __restrict__ W1,
                                                  const float* __restrict__ W2,
                                                  float* __restrict__ xpart,
                                                  float* __restrict__ outpart8) {
    __shared__ float tile[128 * 65];   // [k][b], +1 pad
    int t = threadIdx.x, lane = t & 63, wave = t >> 6;
    int k0 = blockIdx.y * 128;
#pragma unroll
    for (int p = 0; p < 8; ++p) {
        int b = p * 8 + (t >> 5), l5 = t & 31;
        f32x4 h = *(const f32x4*)&hidden[b * 1024 + k0 + l5 * 4];
        tile[(l5 * 4 + 0) * 65 + b] = h.x;
        tile[(l5 * 4 + 1) * 65 + b] = h.y;
        tile[(l5 * 4 + 2) * 65 + b] = h.z;
        tile[(l5 * 4 + 3) * 65 + b] = h.w;
    }
    __syncthreads();
    bool isX = blockIdx.x < 64;
    int cg = isX ? blockIdx.x : blockIdx.x - 64;
    int c_base = cg * 16 + (wave << 2);
    const float* w0p = isX ? (W1 + (size_t)c_base * 1024 + k0)
                           : (W2 + (size_t)c_base * 2048 + 1024 + k0);
    size_t ldw = isX ? 1024 : 2048;
    float acc[4] = {0.f, 0.f, 0.f, 0.f};
    for (int k = 0; k < 128; k += 4) {
        float v0 = tile[(k + 0) * 65 + lane];
        float v1 = tile[(k + 1) * 65 + lane];
        float v2 = tile[(k + 2) * 65 + lane];
        float v3 = tile[(k + 3) * 65 + lane];
#pragma unroll
        for (int oi = 0; oi < 4; ++oi) {
            f32x4 w = *(const f32x4*)&w0p[oi * ldw + k];
            acc[oi] += w.x * v0 + w.y * v1 + w.z * v2 + w.w * v3;
        }
    }
    float* dst = isX ? (xpart + (size_t)blockIdx.y * 65536)
                     : (outpart8 + (size_t)blockIdx.y * 65536);
#pragma unroll
    for (int oi = 0; oi < 4; ++oi)
        dst[(size_t)lane * 1024 + c_base + oi] = acc[oi];
}

// Barrier-free fused scores + mask + per-wave online softmax + ctx partials.
// Trip count derived from len (fully-masked tail groups skipped entirely).
// NOTE: unroll 1 on the g-loop is load-bearing: partial unrolling doubles the
// live e[4][4] tile -> exceeds the 128-VGPR cap from launch_bounds(256,4)
// -> scratch spills in the hot loop (r6/r7 +30us regression).
__global__ __launch_bounds__(256, 4) void k_score(const float* __restrict__ enc,
                                                  const float* __restrict__ xpart,
                                                  const int* __restrict__ src_lens,
                                                  float* __restrict__ scoresG,
                                                  float* __restrict__ ctx_part,
                                                  float* __restrict__ ml_part) {
    int b = blockIdx.y, chunk = blockIdx.x;
    int t = threadIdx.x, lane = t & 63, wave = t >> 6;
    __shared__ f32x4 accbuf[4 * 256];
    __shared__ float mbuf[4], lbuf[4];

    // x[b][:] = sum of 8 K-partials (L2/L3-hot)
    f32x4 xv[4];
#pragma unroll
    for (int i = 0; i < 4; ++i) {
        f32x4 s = (f32x4)0.f;
#pragma unroll
        for (int ks = 0; ks < 8; ++ks)
            s += ((const f32x4*)(xpart + (size_t)ks * 65536 + (size_t)b * 1024))[i * 64 + lane];
        xv[i] = s;
    }
    int len = src_lens[b];
    int s_wave0 = chunk * CHUNK + wave * 16;
    const float* encb = enc + ((size_t)b << 20);

    int rem = len - s_wave0;
    int ng = (rem + 3) >> 2;
    ng = ng < 0 ? 0 : (ng > 4 ? 4 : ng);

    float m_run = -3.0e38f, l_run = 0.f;
    f32x4 acc[4];
#pragma unroll
    for (int i = 0; i < 4; ++i) acc[i] = (f32x4)0.f;

#pragma unroll 1
    for (int g = 0; g < ng; ++g) {
        int sbase = s_wave0 + g * 4;
        f32x4 e[4][4];
#pragma unroll
        for (int j = 0; j < 4; ++j) {
            const f32x4* row4 = (const f32x4*)(encb + (size_t)(sbase + j) * DOUT);
#pragma unroll
            for (int i = 0; i < 4; ++i) e[j][i] = row4[i * 64 + lane];
        }
        float d0 = 0.f, d1 = 0.f, d2 = 0.f, d3 = 0.f;
#pragma unroll
        for (int i = 0; i < 4; ++i) {
            d0 += e[0][i].x * xv[i].x + e[0][i].y * xv[i].y + e[0][i].z * xv[i].z + e[0][i].w * xv[i].w;
            d1 += e[1][i].x * xv[i].x + e[1][i].y * xv[i].y + e[1][i].z * xv[i].z + e[1][i].w * xv[i].w;
            d2 += e[2][i].x * xv[i].x + e[2][i].y * xv[i].y + e[2][i].z * xv[i].z + e[2][i].w * xv[i].w;
            d3 += e[3][i].x * xv[i].x + e[3][i].y * xv[i].y + e[3][i].z * xv[i].z + e[3][i].w * xv[i].w;
        }
#pragma unroll
        for (int off = 32; off > 0; off >>= 1) {
            d0 += __shfl_xor(d0, off, 64);
            d1 += __shfl_xor(d1, off, 64);
            d2 += __shfl_xor(d2, off, 64);
            d3 += __shfl_xor(d3, off, 64);
        }
        // mask: invalid rows -> 0; any exact zero -> -1e10 (reference quirk)
        float v0 = (sbase + 0 < len) ? d0 : 0.f; if (v0 == 0.f) v0 = -1.0e10f;
        float v1 = (sbase + 1 < len) ? d1 : 0.f; if (v1 == 0.f) v1 = -1.0e10f;
        float v2 = (sbase + 2 < len) ? d2 : 0.f; if (v2 == 0.f) v2 = -1.0e10f;
        float v3 = (sbase + 3 < len) ? d3 : 0.f; if (v3 == 0.f) v3 = -1.0e10f;
        if (lane == 0) {
            f32x4 sv = {v0, v1, v2, v3};
            *(f32x4*)&scoresG[b * 1024 + sbase] = sv;
        }
        float msub = fmaxf(fmaxf(v0, v1), fmaxf(v2, v3));
        float m_new = fmaxf(m_run, msub);
        float scale = __expf(m_run - m_new);
        float p0 = __expf(v0 - m_new), p1 = __expf(v1 - m_new);
        float p2 = __expf(v2 - m_new), p3 = __expf(v3 - m_new);
        l_run = l_run * scale + (p0 + p1 + p2 + p3);
        m_run = m_new;
#pragma unroll
        for (int i = 0; i < 4; ++i)
            acc[i] = acc[i] * scale + p0 * e[0][i] + p1 * e[1][i] + p2 * e[2][i] + p3 * e[3][i];
    }

    // block merge (single barrier)
#pragma unroll
    for (int i = 0; i < 4; ++i) accbuf[wave * 256 + i * 64 + lane] = acc[i];
    if (lane == 0) { mbuf[wave] = m_run; lbuf[wave] = l_run; }
    __syncthreads();
    float M = fmaxf(fmaxf(mbuf[0], mbuf[1]), fmaxf(mbuf[2], mbuf[3]));
    float w0 = __expf(mbuf[0] - M), w1 = __expf(mbuf[1] - M);
    float w2 = __expf(mbuf[2] - M), w3 = __expf(mbuf[3] - M);
    f32x4 tot = accbuf[t] * w0 + accbuf[256 + t] * w1 + accbuf[512 + t] * w2 + accbuf[768 + t] * w3;
    ((f32x4*)(ctx_part + ((size_t)(b * SPLIT + chunk) << 10)))[t] = tot;
    if (t == 0) {
        float Lt = lbuf[0] * w0 + lbuf[1] * w1 + lbuf[2] * w2 + lbuf[3] * w3;
        ml_part[(b * SPLIT + chunk) * 2] = M;
        ml_part[(b * SPLIT + chunk) * 2 + 1] = Lt;
    }
}

// Fused finale: ctx-combine + attn-normalize + ctx-half GEMV + hidden-half
// partial sum + tanh. grid 256 = 32 b-pairs x 8 o-chunks(128). block 256.
__global__ __launch_bounds__(256) void k_outfinal(const float* __restrict__ ctx_part,
                                                  const float* __restrict__ ml_part,
                                                  const float* __restrict__ scoresG,
                                                  const int* __restrict__ src_lens,
                                                  const float* __restrict__ outpart8,
                                                  const float* __restrict__ W2,
                                                  float* __restrict__ out,
                                                  float* __restrict__ outAttn) {
    int bp = blockIdx.x >> 3, oq = blockIdx.x & 7;
    int b0 = bp * 2;
    int t = threadIdx.x, lane = t & 63, wave = t >> 6;
    __shared__ float ctx_s[2][1024];
    __shared__ float osum[2][128];

    // softmax stats + ctx combine for both batches
    float inv[2];
#pragma unroll
    for (int bs = 0; bs < 2; ++bs) {
        int b = b0 + bs;
        float M = -3.0e38f;
#pragma unroll
        for (int c = 0; c < SPLIT; ++c) M = fmaxf(M, ml_part[(b * SPLIT + c) * 2]);
        float L = 0.f;
        float wgt[SPLIT];
#pragma unroll
        for (int c = 0; c < SPLIT; ++c) {
            float e = __expf(ml_part[(b * SPLIT + c) * 2] - M);
            wgt[c] = e;
            L += ml_part[(b * SPLIT + c) * 2 + 1] * e;
        }
        inv[bs] = 1.f / L;
#pragma unroll
        for (int r = 0; r < 4; ++r) {
            int d = r * 256 + t;
            float a = 0.f;
#pragma unroll
            for (int c = 0; c < SPLIT; ++c)
                a += wgt[c] * ctx_part[((size_t)(b * SPLIT + c) << 10) + d];
            ctx_s[bs][d] = a * inv[bs];
        }
        if (oq == 0) {   // attn normalize: masked rows underflow to exactly 0
            int len = src_lens[b];
#pragma unroll
            for (int r = 0; r < 4; ++r) {
                int s = r * 256 + t;
                outAttn[s * BSZ + b] = (s < len) ? __expf(scoresG[b * 1024 + s] - M) * inv[bs] : 0.f;
            }
        }
    }

    // hidden-half seed: thread t -> (bsel = t>>7, o_local = t&127)
    int oblk = oq * 128;
    int bsel = t >> 7, o_loc = t & 127;
    float hseed = 0.f;
#pragma unroll
    for (int ks = 0; ks < 8; ++ks)
        hseed += outpart8[(size_t)ks * 65536 + (size_t)(b0 + bsel) * 1024 + oblk + o_loc];
    __syncthreads();

    // ctx-half GEMV: wave w handles o in [oblk + w*32, +32), both batches per W row.
#pragma unroll 2
    for (int i = 0; i < 32; ++i) {
        int o = oblk + wave * 32 + i;
        const f32x4* w4 = (const f32x4*)(W2 + (size_t)o * 2048);
        float s0 = 0.f, s1 = 0.f;
#pragma unroll
        for (int j = 0; j < 4; ++j) {
            f32x4 w = w4[j * 64 + lane];
            f32x4 c0 = ((const f32x4*)ctx_s[0])[j * 64 + lane];
            f32x4 c1 = ((const f32x4*)ctx_s[1])[j * 64 + lane];
            s0 += w.x * c0.x + w.y * c0.y + w.z * c0.z + w.w * c0.w;
            s1 += w.x * c1.x + w.y * c1.y + w.z * c1.z + w.w * c1.w;
        }
#pragma unroll
        for (int off = 32; off > 0; off >>= 1) {
            s0 += __shfl_xor(s0, off, 64);
            s1 += __shfl_xor(s1, off, 64);
        }
        if (lane == 0) { osum[0][wave * 32 + i] = s0; osum[1][wave * 32 + i] = s1; }
    }
    __syncthreads();
    out[(size_t)(b0 + bsel) * 1024 + oblk + o_loc] = tanhf(osum[bsel][o_loc] + hseed);
}

extern "C" void kernel_launch(void* const* d_in, const int* in_sizes, int n_in,
                              void* d_out, int out_size, void* d_ws, size_t ws_size,
                              hipStream_t stream) {
    const float* hidden   = (const float*)d_in[0];
    const float* enc      = (const float*)d_in[1];
    const int*   src_lens = (const int*)d_in[2];
    const float* W1       = (const float*)d_in[3];
    const float* W2       = (const float*)d_in[4];
    float* out     = (float*)d_out;        // [64][1024]
    float* outAttn = out + 65536;          // [1024][64]

    float* ws       = (float*)d_ws;
    float* scoresG  = ws;                  // [64][1024]
    float* ctx_part = ws + 65536;          // [64][16][1024]
    float* ml_part  = ws + 1114112;        // [64][16][2]
    float* xpart    = ws + 1116160;        // [8][64][1024]
    float* outpart8 = ws + 1640448;        // [8][64][1024]

    k_gemv_hid<<<dim3(128, 8), 256, 0, stream>>>(hidden, W1, W2, xpart, outpart8);
    k_score<<<dim3(SPLIT, BSZ), 256, 0, stream>>>(enc, xpart, src_lens, scoresG, ctx_part, ml_part);
    k_outfinal<<<256, 256, 0, stream>>>(ctx_part, ml_part, scoresG, src_lens, outpart8, W2, out, outAttn);
}

// Round 9
// 93.348 us; speedup vs baseline: 3.9930x; 1.0497x over previous
//
#include <hip/hip_runtime.h>
#include <math.h>

// Problem constants
#define BSZ 64
#define SEQ 1024
#define HID 1024
#define DOUT 1024
#define SPLIT 16           // s-chunks per batch -> grid (16,64) for k_score
#define CHUNK (SEQ/SPLIT)  // 64 rows per block; 16 rows per wave

typedef float f32x4 __attribute__((ext_vector_type(4)));

// ws layout (floats):
//  scoresG  [64][1024]       @ 0         (raw masked scores, [b][s])
//  ctxT     [1024][64]       @ 65536     (ctx^T, [d][b])
//  ctx_part [64][16][1024]   @ 131072
//  ml_part  [64][16][2]      @ 1179648
//  xpart    [8][64][1024]    @ 1181696
//  outpart  [16][64][1024]   @ 1705984   (kc 0..7 ctx half, 8..15 hidden half)

// GEMV over hidden: x-partials (W1) AND out-partials for the hidden half of
// W2 (cols k>=1024), sharing one staged hidden tile.
// grid (128, 8): bx<64 -> x cols, bx>=64 -> out cols. by = 128-wide k-chunk.
__global__ __launch_bounds__(256) void k_gemv_hid(const float* __restrict__ hidden,
                                                  const float* __restrict__ W1,
                                                  const float* __restrict__ W2,
                                                  float* __restrict__ xpart,
                                                  float* __restrict__ outpart) {
    __shared__ float tile[128 * 65];   // [k][b], +1 pad
    int t = threadIdx.x, lane = t & 63, wave = t >> 6;
    int k0 = blockIdx.y * 128;
#pragma unroll
    for (int p = 0; p < 8; ++p) {
        int b = p * 8 + (t >> 5), l5 = t & 31;
        f32x4 h = *(const f32x4*)&hidden[b * 1024 + k0 + l5 * 4];
        tile[(l5 * 4 + 0) * 65 + b] = h.x;
        tile[(l5 * 4 + 1) * 65 + b] = h.y;
        tile[(l5 * 4 + 2) * 65 + b] = h.z;
        tile[(l5 * 4 + 3) * 65 + b] = h.w;
    }
    __syncthreads();
    bool isX = blockIdx.x < 64;
    int cg = isX ? blockIdx.x : blockIdx.x - 64;
    int c_base = cg * 16 + (wave << 2);
    const float* w0p = isX ? (W1 + (size_t)c_base * 1024 + k0)
                           : (W2 + (size_t)c_base * 2048 + 1024 + k0);
    size_t ldw = isX ? 1024 : 2048;
    float acc[4] = {0.f, 0.f, 0.f, 0.f};
    for (int k = 0; k < 128; k += 4) {
        float v0 = tile[(k + 0) * 65 + lane];
        float v1 = tile[(k + 1) * 65 + lane];
        float v2 = tile[(k + 2) * 65 + lane];
        float v3 = tile[(k + 3) * 65 + lane];
#pragma unroll
        for (int oi = 0; oi < 4; ++oi) {
            f32x4 w = *(const f32x4*)&w0p[oi * ldw + k];
            acc[oi] += w.x * v0 + w.y * v1 + w.z * v2 + w.w * v3;
        }
    }
    float* dst = isX ? (xpart + (size_t)blockIdx.y * 65536)
                     : (outpart + (size_t)(8 + blockIdx.y) * 65536);
#pragma unroll
    for (int oi = 0; oi < 4; ++oi)
        dst[(size_t)lane * 1024 + c_base + oi] = acc[oi];
}

// Barrier-free fused scores + mask + per-wave online softmax + ctx partials.
// Trip count derived from len (fully-masked tail groups skipped entirely).
// unroll 1 keeps one live e[4][4] tile (VGPR cap 128 from launch_bounds(256,4)).
__global__ __launch_bounds__(256, 4) void k_score(const float* __restrict__ enc,
                                                  const float* __restrict__ xpart,
                                                  const int* __restrict__ src_lens,
                                                  float* __restrict__ scoresG,
                                                  float* __restrict__ ctx_part,
                                                  float* __restrict__ ml_part) {
    int b = blockIdx.y, chunk = blockIdx.x;
    int t = threadIdx.x, lane = t & 63, wave = t >> 6;
    __shared__ f32x4 accbuf[4 * 256];
    __shared__ float mbuf[4], lbuf[4];

    // x[b][:] = sum of 8 K-partials (L2/L3-hot)
    f32x4 xv[4];
#pragma unroll
    for (int i = 0; i < 4; ++i) {
        f32x4 s = (f32x4)0.f;
#pragma unroll
        for (int ks = 0; ks < 8; ++ks)
            s += ((const f32x4*)(xpart + (size_t)ks * 65536 + (size_t)b * 1024))[i * 64 + lane];
        xv[i] = s;
    }
    int len = src_lens[b];
    int s_wave0 = chunk * CHUNK + wave * 16;
    const float* encb = enc + ((size_t)b << 20);

    int rem = len - s_wave0;
    int ng = (rem + 3) >> 2;
    ng = ng < 0 ? 0 : (ng > 4 ? 4 : ng);

    float m_run = -3.0e38f, l_run = 0.f;
    f32x4 acc[4];
#pragma unroll
    for (int i = 0; i < 4; ++i) acc[i] = (f32x4)0.f;

#pragma unroll 1
    for (int g = 0; g < ng; ++g) {
        int sbase = s_wave0 + g * 4;
        f32x4 e[4][4];
#pragma unroll
        for (int j = 0; j < 4; ++j) {
            const f32x4* row4 = (const f32x4*)(encb + (size_t)(sbase + j) * DOUT);
#pragma unroll
            for (int i = 0; i < 4; ++i) e[j][i] = row4[i * 64 + lane];
        }
        float d0 = 0.f, d1 = 0.f, d2 = 0.f, d3 = 0.f;
#pragma unroll
        for (int i = 0; i < 4; ++i) {
            d0 += e[0][i].x * xv[i].x + e[0][i].y * xv[i].y + e[0][i].z * xv[i].z + e[0][i].w * xv[i].w;
            d1 += e[1][i].x * xv[i].x + e[1][i].y * xv[i].y + e[1][i].z * xv[i].z + e[1][i].w * xv[i].w;
            d2 += e[2][i].x * xv[i].x + e[2][i].y * xv[i].y + e[2][i].z * xv[i].z + e[2][i].w * xv[i].w;
            d3 += e[3][i].x * xv[i].x + e[3][i].y * xv[i].y + e[3][i].z * xv[i].z + e[3][i].w * xv[i].w;
        }
#pragma unroll
        for (int off = 32; off > 0; off >>= 1) {
            d0 += __shfl_xor(d0, off, 64);
            d1 += __shfl_xor(d1, off, 64);
            d2 += __shfl_xor(d2, off, 64);
            d3 += __shfl_xor(d3, off, 64);
        }
        // mask: invalid rows -> 0; any exact zero -> -1e10 (reference quirk)
        float v0 = (sbase + 0 < len) ? d0 : 0.f; if (v0 == 0.f) v0 = -1.0e10f;
        float v1 = (sbase + 1 < len) ? d1 : 0.f; if (v1 == 0.f) v1 = -1.0e10f;
        float v2 = (sbase + 2 < len) ? d2 : 0.f; if (v2 == 0.f) v2 = -1.0e10f;
        float v3 = (sbase + 3 < len) ? d3 : 0.f; if (v3 == 0.f) v3 = -1.0e10f;
        if (lane == 0) {
            f32x4 sv = {v0, v1, v2, v3};
            *(f32x4*)&scoresG[b * 1024 + sbase] = sv;
        }
        float msub = fmaxf(fmaxf(v0, v1), fmaxf(v2, v3));
        float m_new = fmaxf(m_run, msub);
        float scale = __expf(m_run - m_new);
        float p0 = __expf(v0 - m_new), p1 = __expf(v1 - m_new);
        float p2 = __expf(v2 - m_new), p3 = __expf(v3 - m_new);
        l_run = l_run * scale + (p0 + p1 + p2 + p3);
        m_run = m_new;
#pragma unroll
        for (int i = 0; i < 4; ++i)
            acc[i] = acc[i] * scale + p0 * e[0][i] + p1 * e[1][i] + p2 * e[2][i] + p3 * e[3][i];
    }

    // block merge (single barrier)
#pragma unroll
    for (int i = 0; i < 4; ++i) accbuf[wave * 256 + i * 64 + lane] = acc[i];
    if (lane == 0) { mbuf[wave] = m_run; lbuf[wave] = l_run; }
    __syncthreads();
    float M = fmaxf(fmaxf(mbuf[0], mbuf[1]), fmaxf(mbuf[2], mbuf[3]));
    float w0 = __expf(mbuf[0] - M), w1 = __expf(mbuf[1] - M);
    float w2 = __expf(mbuf[2] - M), w3 = __expf(mbuf[3] - M);
    f32x4 tot = accbuf[t] * w0 + accbuf[256 + t] * w1 + accbuf[512 + t] * w2 + accbuf[768 + t] * w3;
    ((f32x4*)(ctx_part + ((size_t)(b * SPLIT + chunk) << 10)))[t] = tot;
    if (t == 0) {
        float Lt = lbuf[0] * w0 + lbuf[1] * w1 + lbuf[2] * w2 + lbuf[3] * w3;
        ml_part[(b * SPLIT + chunk) * 2] = M;
        ml_part[(b * SPLIT + chunk) * 2 + 1] = Lt;
    }
}

// Per-batch combine + attn normalize. grid 256: b = bid>>2, quarter = bid&3.
__global__ __launch_bounds__(256) void k_reduce_attn(const float* __restrict__ ctx_part,
                                                     const float* __restrict__ ml_part,
                                                     const float* __restrict__ scoresG,
                                                     const int* __restrict__ src_lens,
                                                     float* __restrict__ ctxT,
                                                     float* __restrict__ outAttn) {
    int b = blockIdx.x >> 2, q = blockIdx.x & 3, t = threadIdx.x;
    int len = src_lens[b];
    float M = -3.0e38f;
#pragma unroll
    for (int c = 0; c < SPLIT; ++c) M = fmaxf(M, ml_part[(b * SPLIT + c) * 2]);
    float L = 0.f;
    float wgt[SPLIT];
#pragma unroll
    for (int c = 0; c < SPLIT; ++c) {
        float e = __expf(ml_part[(b * SPLIT + c) * 2] - M);
        wgt[c] = e;
        L += ml_part[(b * SPLIT + c) * 2 + 1] * e;
    }
    float inv = 1.f / L;
    int d = q * 256 + t;
    float acc = 0.f;
#pragma unroll
    for (int c = 0; c < SPLIT; ++c)
        acc += wgt[c] * ctx_part[((size_t)(b * SPLIT + c) << 10) + d];
    ctxT[d * BSZ + b] = acc * inv;
    // masked rows: reference exp(-1e10 - M) underflows to exactly 0
    outAttn[d * BSZ + b] = (d < len) ? __expf(scoresG[b * 1024 + d] - M) * inv : 0.f;
}

// ctx half of the output GEMM: grid (64, 8), k0 = by*128 over ctxT[d][b].
// Each W2 element read exactly once.
__global__ __launch_bounds__(256) void k_out_part(const float* __restrict__ W2,
                                                  const float* __restrict__ ctxT,
                                                  float* __restrict__ outpart) {
    __shared__ float tile[128 * 64];
    int t = threadIdx.x, lane = t & 63, wave = t >> 6;
    int k0 = blockIdx.y * 128;
    int c_base = blockIdx.x * 16 + (wave << 2);
    {
        const f32x4* src = (const f32x4*)(ctxT + (size_t)k0 * 64);
        f32x4* dst = (f32x4*)tile;
#pragma unroll
        for (int i = 0; i < 8; ++i) dst[t + i * 256] = src[t + i * 256];
    }
    __syncthreads();
    float acc[4] = {0.f, 0.f, 0.f, 0.f};
    for (int k = 0; k < 128; k += 4) {
        float v0 = tile[(k + 0) * 64 + lane];
        float v1 = tile[(k + 1) * 64 + lane];
        float v2 = tile[(k + 2) * 64 + lane];
        float v3 = tile[(k + 3) * 64 + lane];
#pragma unroll
        for (int oi = 0; oi < 4; ++oi) {
            f32x4 w = *(const f32x4*)&W2[(size_t)(c_base + oi) * 2048 + k0 + k];
            acc[oi] += w.x * v0 + w.y * v1 + w.z * v2 + w.w * v3;
        }
    }
#pragma unroll
    for (int oi = 0; oi < 4; ++oi)
        outpart[(size_t)blockIdx.y * 65536 + (size_t)lane * 1024 + c_base + oi] = acc[oi];
}

__global__ void k_out_reduce(const float* __restrict__ outpart, float* __restrict__ out) {
    int idx = blockIdx.x * 256 + threadIdx.x;
    float s = 0.f;
#pragma unroll
    for (int ks = 0; ks < 16; ++ks) s += outpart[(size_t)ks * 65536 + idx];
    out[idx] = tanhf(s);
}

extern "C" void kernel_launch(void* const* d_in, const int* in_sizes, int n_in,
                              void* d_out, int out_size, void* d_ws, size_t ws_size,
                              hipStream_t stream) {
    const float* hidden   = (const float*)d_in[0];
    const float* enc      = (const float*)d_in[1];
    const int*   src_lens = (const int*)d_in[2];
    const float* W1       = (const float*)d_in[3];
    const float* W2       = (const float*)d_in[4];
    float* out     = (float*)d_out;        // [64][1024]
    float* outAttn = out + 65536;          // [1024][64]

    float* ws       = (float*)d_ws;
    float* scoresG  = ws;                  // [64][1024]
    float* ctxT     = ws + 65536;          // [1024][64]
    float* ctx_part = ws + 131072;         // [64][16][1024]
    float* ml_part  = ws + 1179648;        // [64][16][2]
    float* xpart    = ws + 1181696;        // [8][64][1024]
    float* outpart  = ws + 1705984;        // [16][64][1024]

    k_gemv_hid<<<dim3(128, 8), 256, 0, stream>>>(hidden, W1, W2, xpart, outpart);
    k_score<<<dim3(SPLIT, BSZ), 256, 0, stream>>>(enc, xpart, src_lens, scoresG, ctx_part, ml_part);
    k_reduce_attn<<<256, 256, 0, stream>>>(ctx_part, ml_part, scoresG, src_lens, ctxT, outAttn);
    k_out_part<<<dim3(64, 8), 256, 0, stream>>>(W2, ctxT, outpart);
    k_out_reduce<<<256, 256, 0, stream>>>(outpart, out);
}

// Round 10
// 72.194 us; speedup vs baseline: 5.1630x; 1.2930x over previous
//
#include <hip/hip_runtime.h>
#include <math.h>

// Problem constants
#define BSZ 64
#define SEQ 1024
#define HID 1024
#define DOUT 1024
#define SPLIT 16           // s-chunks per batch -> grid (16,64) for k_score
#define CHUNK (SEQ/SPLIT)  // 64 rows per block; 16 rows per wave

typedef float f32x4 __attribute__((ext_vector_type(4)));

// ws layout (floats):
//  scoresG  [1024][64]       @ 0
//  ctxT     [1024][64]       @ 65536
//  ctx_part [64][16][1024]   @ 131072
//  ml_part  [64][16][2]      @ 1179648
//  xpart    [8][64][1024]    @ 1181696
//  outpart  [16][64][1024]   @ 1705984

// GEMV over hidden: x-partials (W1) AND out-partials for the hidden half of
// W2 (cols k>=1024), sharing one staged hidden tile.
// grid (128, 8): bx<64 -> x cols, bx>=64 -> out cols. by = 128-wide k-chunk.
__global__ __launch_bounds__(256) void k_gemv_hid(const float* __restrict__ hidden,
                                                  const float* __restrict__ W1,
                                                  const float* __restrict__ W2,
                                                  float* __restrict__ xpart,
                                                  float* __restrict__ outpart) {
    __shared__ float tile[128 * 65];   // [k][b], +1 pad
    int t = threadIdx.x, lane = t & 63, wave = t >> 6;
    int k0 = blockIdx.y * 128;
#pragma unroll
    for (int p = 0; p < 8; ++p) {
        int b = p * 8 + (t >> 5), l5 = t & 31;
        f32x4 h = *(const f32x4*)&hidden[b * 1024 + k0 + l5 * 4];
        tile[(l5 * 4 + 0) * 65 + b] = h.x;
        tile[(l5 * 4 + 1) * 65 + b] = h.y;
        tile[(l5 * 4 + 2) * 65 + b] = h.z;
        tile[(l5 * 4 + 3) * 65 + b] = h.w;
    }
    __syncthreads();
    bool isX = blockIdx.x < 64;
    int cg = isX ? blockIdx.x : blockIdx.x - 64;
    int c_base = cg * 16 + (wave << 2);
    const float* w0p = isX ? (W1 + (size_t)c_base * 1024 + k0)
                           : (W2 + (size_t)c_base * 2048 + 1024 + k0);
    size_t ldw = isX ? 1024 : 2048;
    float acc[4] = {0.f, 0.f, 0.f, 0.f};
    for (int k = 0; k < 128; k += 4) {
        float v0 = tile[(k + 0) * 65 + lane];
        float v1 = tile[(k + 1) * 65 + lane];
        float v2 = tile[(k + 2) * 65 + lane];
        float v3 = tile[(k + 3) * 65 + lane];
#pragma unroll
        for (int oi = 0; oi < 4; ++oi) {
            f32x4 w = *(const f32x4*)&w0p[oi * ldw + k];
            acc[oi] += w.x * v0 + w.y * v1 + w.z * v2 + w.w * v3;
        }
    }
    float* dst = isX ? (xpart + (size_t)blockIdx.y * 65536)
                     : (outpart + (size_t)(8 + blockIdx.y) * 65536);
#pragma unroll
    for (int oi = 0; oi < 4; ++oi)
        dst[(size_t)lane * 1024 + c_base + oi] = acc[oi];
}

// Barrier-free fused scores + mask + per-wave online softmax + ctx partials.
// Fixed-trip group loop with in-body wave-uniform skip (r4-verified codegen).
__global__ __launch_bounds__(256, 4) void k_score(const float* __restrict__ enc,
                                                  const float* __restrict__ xpart,
                                                  const int* __restrict__ src_lens,
                                                  float* __restrict__ scoresG,
                                                  float* __restrict__ ctx_part,
                                                  float* __restrict__ ml_part) {
    int b = blockIdx.y, chunk = blockIdx.x;
    int t = threadIdx.x, lane = t & 63, wave = t >> 6;
    __shared__ f32x4 accbuf[4 * 256];
    __shared__ float mbuf[4], lbuf[4];

    // x[b][:] = sum of 8 K-partials (L2-hot)
    f32x4 xv[4];
#pragma unroll
    for (int i = 0; i < 4; ++i) {
        f32x4 s = (f32x4)0.f;
#pragma unroll
        for (int ks = 0; ks < 8; ++ks)
            s += ((const f32x4*)(xpart + (size_t)ks * 65536 + (size_t)b * 1024))[i * 64 + lane];
        xv[i] = s;
    }
    int len = src_lens[b];
    int s_wave0 = chunk * CHUNK + wave * 16;
    const float* encb = enc + ((size_t)b << 20);

    float m_run = -3.0e38f, l_run = 0.f;
    f32x4 acc[4];
#pragma unroll
    for (int i = 0; i < 4; ++i) acc[i] = (f32x4)0.f;

#pragma unroll 1
    for (int g = 0; g < 4; ++g) {
        int sbase = s_wave0 + g * 4;
        if (sbase >= len) {   // fully-masked group: weight underflows to 0, skip loads
            if (lane == 0) {
#pragma unroll
                for (int j = 0; j < 4; ++j) scoresG[(sbase + j) * BSZ + b] = -1.0e10f;
            }
            continue;
        }
        f32x4 e[4][4];
#pragma unroll
        for (int j = 0; j < 4; ++j) {
            const f32x4* row4 = (const f32x4*)(encb + (size_t)(sbase + j) * DOUT);
#pragma unroll
            for (int i = 0; i < 4; ++i) e[j][i] = row4[i * 64 + lane];
        }
        float d0 = 0.f, d1 = 0.f, d2 = 0.f, d3 = 0.f;
#pragma unroll
        for (int i = 0; i < 4; ++i) {
            d0 += e[0][i].x * xv[i].x + e[0][i].y * xv[i].y + e[0][i].z * xv[i].z + e[0][i].w * xv[i].w;
            d1 += e[1][i].x * xv[i].x + e[1][i].y * xv[i].y + e[1][i].z * xv[i].z + e[1][i].w * xv[i].w;
            d2 += e[2][i].x * xv[i].x + e[2][i].y * xv[i].y + e[2][i].z * xv[i].z + e[2][i].w * xv[i].w;
            d3 += e[3][i].x * xv[i].x + e[3][i].y * xv[i].y + e[3][i].z * xv[i].z + e[3][i].w * xv[i].w;
        }
#pragma unroll
        for (int off = 32; off > 0; off >>= 1) {
            d0 += __shfl_xor(d0, off, 64);
            d1 += __shfl_xor(d1, off, 64);
            d2 += __shfl_xor(d2, off, 64);
            d3 += __shfl_xor(d3, off, 64);
        }
        // mask: invalid rows -> 0; any exact zero -> -1e10 (reference quirk)
        float v0 = (sbase + 0 < len) ? d0 : 0.f; if (v0 == 0.f) v0 = -1.0e10f;
        float v1 = (sbase + 1 < len) ? d1 : 0.f; if (v1 == 0.f) v1 = -1.0e10f;
        float v2 = (sbase + 2 < len) ? d2 : 0.f; if (v2 == 0.f) v2 = -1.0e10f;
        float v3 = (sbase + 3 < len) ? d3 : 0.f; if (v3 == 0.f) v3 = -1.0e10f;
        if (lane == 0) {
            scoresG[(sbase + 0) * BSZ + b] = v0;
            scoresG[(sbase + 1) * BSZ + b] = v1;
            scoresG[(sbase + 2) * BSZ + b] = v2;
            scoresG[(sbase + 3) * BSZ + b] = v3;
        }
        float msub = fmaxf(fmaxf(v0, v1), fmaxf(v2, v3));
        float m_new = fmaxf(m_run, msub);
        float scale = __expf(m_run - m_new);
        float p0 = __expf(v0 - m_new), p1 = __expf(v1 - m_new);
        float p2 = __expf(v2 - m_new), p3 = __expf(v3 - m_new);
        l_run = l_run * scale + (p0 + p1 + p2 + p3);
        m_run = m_new;
#pragma unroll
        for (int i = 0; i < 4; ++i)
            acc[i] = acc[i] * scale + p0 * e[0][i] + p1 * e[1][i] + p2 * e[2][i] + p3 * e[3][i];
    }

    // block merge (single barrier)
#pragma unroll
    for (int i = 0; i < 4; ++i) accbuf[wave * 256 + i * 64 + lane] = acc[i];
    if (lane == 0) { mbuf[wave] = m_run; lbuf[wave] = l_run; }
    __syncthreads();
    float M = fmaxf(fmaxf(mbuf[0], mbuf[1]), fmaxf(mbuf[2], mbuf[3]));
    float w0 = __expf(mbuf[0] - M), w1 = __expf(mbuf[1] - M);
    float w2 = __expf(mbuf[2] - M), w3 = __expf(mbuf[3] - M);
    f32x4 tot = accbuf[t] * w0 + accbuf[256 + t] * w1 + accbuf[512 + t] * w2 + accbuf[768 + t] * w3;
    ((f32x4*)(ctx_part + ((size_t)(b * SPLIT + chunk) << 10)))[t] = tot;
    if (t == 0) {
        float Lt = lbuf[0] * w0 + lbuf[1] * w1 + lbuf[2] * w2 + lbuf[3] * w3;
        ml_part[(b * SPLIT + chunk) * 2] = M;
        ml_part[(b * SPLIT + chunk) * 2 + 1] = Lt;
    }
}

// Per-batch combine + attn normalize. grid 256: b = bid>>2, quarter = bid&3.
__global__ __launch_bounds__(256) void k_reduce_attn(const float* __restrict__ ctx_part,
                                                     const float* __restrict__ ml_part,
                                                     const float* __restrict__ scoresG,
                                                     float* __restrict__ ctxT,
                                                     float* __restrict__ outAttn) {
    int b = blockIdx.x >> 2, q = blockIdx.x & 3, t = threadIdx.x;
    float M = -3.0e38f;
#pragma unroll
    for (int c = 0; c < SPLIT; ++c) M = fmaxf(M, ml_part[(b * SPLIT + c) * 2]);
    float L = 0.f;
    float wgt[SPLIT];
#pragma unroll
    for (int c = 0; c < SPLIT; ++c) {
        float e = __expf(ml_part[(b * SPLIT + c) * 2] - M);
        wgt[c] = e;
        L += ml_part[(b * SPLIT + c) * 2 + 1] * e;
    }
    float inv = 1.f / L;
    int d = q * 256 + t;
    float acc = 0.f;
#pragma unroll
    for (int c = 0; c < SPLIT; ++c)
        acc += wgt[c] * ctx_part[((size_t)(b * SPLIT + c) << 10) + d];
    ctxT[d * BSZ + b] = acc * inv;
    outAttn[d * BSZ + b] = __expf(scoresG[d * BSZ + b] - M) * inv;  // d doubles as s
}

// ctx half of the output GEMM: grid (64, 8), k0 = by*128 over ctxT[d][b].
__global__ __launch_bounds__(256) void k_out_part(const float* __restrict__ W2,
                                                  const float* __restrict__ ctxT,
                                                  float* __restrict__ outpart) {
    __shared__ float tile[128 * 64];
    int t = threadIdx.x, lane = t & 63, wave = t >> 6;
    int k0 = blockIdx.y * 128;
    int c_base = blockIdx.x * 16 + (wave << 2);
    {
        const f32x4* src = (const f32x4*)(ctxT + k0 * 64);
        f32x4* dst = (f32x4*)tile;
#pragma unroll
        for (int i = 0; i < 8; ++i) dst[t + i * 256] = src[t + i * 256];
    }
    __syncthreads();
    float acc[4] = {0.f, 0.f, 0.f, 0.f};
    for (int k = 0; k < 128; k += 4) {
        float v0 = tile[(k + 0) * 64 + lane];
        float v1 = tile[(k + 1) * 64 + lane];
        float v2 = tile[(k + 2) * 64 + lane];
        float v3 = tile[(k + 3) * 64 + lane];
#pragma unroll
        for (int oi = 0; oi < 4; ++oi) {
            f32x4 w = *(const f32x4*)&W2[(size_t)(c_base + oi) * 2048 + k0 + k];
            acc[oi] += w.x * v0 + w.y * v1 + w.z * v2 + w.w * v3;
        }
    }
#pragma unroll
    for (int oi = 0; oi < 4; ++oi)
        outpart[(size_t)blockIdx.y * 65536 + (size_t)lane * 1024 + c_base + oi] = acc[oi];
}

__global__ void k_out_reduce(const float* __restrict__ outpart, float* __restrict__ out) {
    int idx = blockIdx.x * 256 + threadIdx.x;
    float s = 0.f;
#pragma unroll
    for (int ks = 0; ks < 16; ++ks) s += outpart[(size_t)ks * 65536 + idx];
    out[idx] = tanhf(s);
}

extern "C" void kernel_launch(void* const* d_in, const int* in_sizes, int n_in,
                              void* d_out, int out_size, void* d_ws, size_t ws_size,
                              hipStream_t stream) {
    const float* hidden   = (const float*)d_in[0];
    const float* enc      = (const float*)d_in[1];
    const int*   src_lens = (const int*)d_in[2];
    const float* W1       = (const float*)d_in[3];
    const float* W2       = (const float*)d_in[4];
    float* out     = (float*)d_out;        // [64][1024]
    float* outAttn = out + 65536;          // [1024][64]

    float* ws       = (float*)d_ws;
    float* scoresG  = ws;                  // [1024][64]
    float* ctxT     = ws + 65536;          // [1024][64]
    float* ctx_part = ws + 131072;         // [64][16][1024]
    float* ml_part  = ws + 1179648;        // [64][16][2]
    float* xpart    = ws + 1181696;        // [8][64][1024]
    float* outpart  = ws + 1705984;        // [16][64][1024]

    k_gemv_hid<<<dim3(128, 8), 256, 0, stream>>>(hidden, W1, W2, xpart, outpart);
    k_score<<<dim3(SPLIT, BSZ), 256, 0, stream>>>(enc, xpart, src_lens, scoresG, ctx_part, ml_part);
    k_reduce_attn<<<256, 256, 0, stream>>>(ctx_part, ml_part, scoresG, ctxT, outAttn);
    k_out_part<<<dim3(64, 8), 256, 0, stream>>>(W2, ctxT, outpart);
    k_out_reduce<<<256, 256, 0, stream>>>(outpart, out);
}